// Round 3
// baseline (198.869 us; speedup 1.0000x reference)
//
#include <hip/hip_runtime.h>
#include <hip/hip_fp16.h>

#define BB 4
#define SS 4096
#define DD 64
#define NSPLIT 8                 // K-split factor: 1024 blocks = 4/CU = 16 waves/CU
#define KT_PER (SS / 64 / NSPLIT)

typedef _Float16 half8 __attribute__((ext_vector_type(8)));
typedef _Float16 half4 __attribute__((ext_vector_type(4)));
typedef __fp16 fp16x2 __attribute__((ext_vector_type(2)));   // cvt_pkrtz return type
typedef float floatx4 __attribute__((ext_vector_type(4)));
typedef float floatx16 __attribute__((ext_vector_type(16)));

// Kernel A: Q = X*R, K = X*E in fp32, stored as hi/lo fp16 pairs (Markidis split).
__global__ __launch_bounds__(256) void proj_kernel(
    const float* __restrict__ X, const float* __restrict__ R, const float* __restrict__ E,
    _Float16* __restrict__ Qhi, _Float16* __restrict__ Qlo,
    _Float16* __restrict__ Khi, _Float16* __restrict__ Klo,
    _Float16* __restrict__ Vt)
{
    __shared__ float Rs[64][64];
    __shared__ float Es[64][64];
    __shared__ float Xs[16][68];     // pad 68 breaks stride-64 conflicts on transposed reads
    int t = threadIdx.x;
    long rowbase = (long)blockIdx.x * 16;

    for (int j = 0; j < 4; ++j) {
        int idx = j * 256 + t;       // 1024 float4 per 64x64 matrix
        int r = idx >> 4;
        int c = (idx & 15) * 4;
        *(float4*)&Rs[r][c] = ((const float4*)R)[idx];
        *(float4*)&Es[r][c] = ((const float4*)E)[idx];
    }
    *(float4*)&Xs[t >> 4][(t & 15) * 4] = ((const float4*)(X + rowbase * 64))[t];
    __syncthreads();

    int row = t >> 4;                // 0..15
    int c0 = (t & 15) * 4;           // 0..60
    float q[4] = {0.f, 0.f, 0.f, 0.f}, k[4] = {0.f, 0.f, 0.f, 0.f};
#pragma unroll 4
    for (int d = 0; d < 64; ++d) {
        float x = Xs[row][d];
        float4 rv = *(const float4*)&Rs[d][c0];   // ds_read_b128
        float4 ev = *(const float4*)&Es[d][c0];
        q[0] = fmaf(x, rv.x, q[0]); q[1] = fmaf(x, rv.y, q[1]);
        q[2] = fmaf(x, rv.z, q[2]); q[3] = fmaf(x, rv.w, q[3]);
        k[0] = fmaf(x, ev.x, k[0]); k[1] = fmaf(x, ev.y, k[1]);
        k[2] = fmaf(x, ev.z, k[2]); k[3] = fmaf(x, ev.w, k[3]);
    }
    long gq = (rowbase + row) * 64 + c0;
    half4 qh, ql, kh, kl;
    for (int j = 0; j < 4; ++j) {
        _Float16 h = (_Float16)q[j];
        qh[j] = h; ql[j] = (_Float16)(q[j] - (float)h);
        h = (_Float16)k[j];
        kh[j] = h; kl[j] = (_Float16)(k[j] - (float)h);
    }
    *(half4*)(Qhi + gq) = qh; *(half4*)(Qlo + gq) = ql;
    *(half4*)(Khi + gq) = kh; *(half4*)(Klo + gq) = kl;

    // V^T: Vt[b][d][s] = X[b][s][d] fp16
    int d = t >> 2;                  // 0..63
    int si = (t & 3) * 4;            // 0..12
    int b = (int)(rowbase >> 12);
    int sbase = (int)(rowbase & 4095);
    half4 v;
    for (int j = 0; j < 4; ++j) v[j] = (_Float16)Xs[si + j][d];
    *(half4*)(Vt + ((long)(b * 64 + d)) * SS + sbase + si) = v;
}

#define L2E 1.44269504088896340736f

// Kernel B: flash attention partial, ZERO LDS.
// 32x32x16 MFMA, 32 queries/wave, S^T layout (A=K, B=Q) so each lane owns ONE
// query column (lane&31); partner lane is lane^32 (one shfl_xor per reduction).
// K/V fragments load straight from global (L1/L2-resident, shared by the 4 waves).
// P stays in registers: v_permlane32_swap_b32 builds the PV A-fragments (T12).
// R2: the compiler sinks the "prefetch" loads to their uses (VGPR=84) — latency
// is hidden by TLP instead: NSPLIT=8 -> 1024 blocks = 4 blocks/CU = 16 waves/CU.
__global__ __launch_bounds__(256, 4) void attn_partial(
    const _Float16* __restrict__ Qhi, const _Float16* __restrict__ Qlo,
    const _Float16* __restrict__ Khi, const _Float16* __restrict__ Klo,
    const _Float16* __restrict__ Vt,
    float* __restrict__ Op, float* __restrict__ Mp, float* __restrict__ Lp)
{
    int t = threadIdx.x;
    int wave = t >> 6;
    int lane = t & 63;
    int col = lane & 31;             // query column (QK C) == query row (PV A) == d col (PV C)
    int h = lane >> 5;               // lane half

    // XCD-aware decode: dispatch round-robins XCD = lin&7; give each XCD 4
    // contiguous (b,split) K-ranges so its L2 working set is ~770 KB.
    int lin = blockIdx.x;            // 0..1023
    int xcd = lin & 7;
    int idx = lin >> 3;              // 0..127
    int combo = xcd * 4 + (idx >> 5);// 0..31  (b,split) pair
    int qt = idx & 31;
    int b = combo >> 3;
    int split = combo & 7;

    int q0w = qt * 128 + wave * 32;

    const float scale = 0.125f * L2E;

    // Q B-fragments: B[k=dc*16+h*8+j][query=col], contiguous in Qhi[q][d]
    long qbase = ((long)b * SS + q0w + col) * DD + h * 8;
    half8 qh[4], ql[4];
#pragma unroll
    for (int dc = 0; dc < 4; ++dc) {
        qh[dc] = *(const half8*)(Qhi + qbase + dc * 16);
        ql[dc] = *(const half8*)(Qlo + qbase + dc * 16);
    }

    int kt0 = split * KT_PER;
    long koff = ((long)b * SS + (long)kt0 * 64 + col) * DD + h * 8;
    long voff = ((long)b * 64 + col) * SS + kt0 * 64 + h * 8;

    // tile-0 operand fragments (register-rotated each iteration; compiler may
    // sink these to use-points — fine, TLP covers the latency)
    half8 kh[2][4], kl[2][4], vb[4][2];
#pragma unroll
    for (int kb = 0; kb < 2; ++kb)
#pragma unroll
        for (int dc = 0; dc < 4; ++dc) {
            kh[kb][dc] = *(const half8*)(Khi + koff + kb * 32 * DD + dc * 16);
            kl[kb][dc] = *(const half8*)(Klo + koff + kb * 32 * DD + dc * 16);
        }
#pragma unroll
    for (int kc = 0; kc < 4; ++kc)
#pragma unroll
        for (int db = 0; db < 2; ++db)
            vb[kc][db] = *(const half8*)(Vt + voff + (long)db * 32 * SS + kc * 16);

    floatx16 o0 = {}, o1 = {};
    float m_q = -1e30f, l_q = 0.f;

#pragma unroll 1
    for (int it = 0; it < KT_PER; ++it) {
        // S^T = K Q^T (fp32-accurate, 3-term Markidis): C[key][query=col]
        floatx16 s[2] = {};
#pragma unroll
        for (int dc = 0; dc < 4; ++dc) {
            s[0] = __builtin_amdgcn_mfma_f32_32x32x16_f16(kh[0][dc], qh[dc], s[0], 0, 0, 0);
            s[1] = __builtin_amdgcn_mfma_f32_32x32x16_f16(kh[1][dc], qh[dc], s[1], 0, 0, 0);
            s[0] = __builtin_amdgcn_mfma_f32_32x32x16_f16(kh[0][dc], ql[dc], s[0], 0, 0, 0);
            s[1] = __builtin_amdgcn_mfma_f32_32x32x16_f16(kh[1][dc], ql[dc], s[1], 0, 0, 0);
            s[0] = __builtin_amdgcn_mfma_f32_32x32x16_f16(kl[0][dc], qh[dc], s[0], 0, 0, 0);
            s[1] = __builtin_amdgcn_mfma_f32_32x32x16_f16(kl[1][dc], qh[dc], s[1], 0, 0, 0);
        }

        // per-query max: 32 in-lane values + one partner exchange
        float mt = s[0][0];
#pragma unroll
        for (int r = 1; r < 16; ++r) mt = fmaxf(mt, s[0][r]);
#pragma unroll
        for (int r = 0; r < 16; ++r) mt = fmaxf(mt, s[1][r]);
        mt = fmaxf(mt, __shfl_xor(mt, 32));
        mt *= scale;

        // defer-max (T13): only rescale when some query's max grew by >8 (exp2 dom)
        if (!__all(mt <= m_q + 8.f)) {
            float mn = fmaxf(m_q, mt);
            float alpha = exp2f(m_q - mn);     // 0 on first tile
            m_q = mn;
            l_q *= alpha;
#pragma unroll
            for (int r = 0; r < 16; ++r) {     // o rows are queries: gather that query's alpha
                float a = __shfl(alpha, (r & 3) + 8 * (r >> 2) + 4 * h);
                o0[r] *= a; o1[r] *= a;
            }
        }

        // exp + fp16 pack. Lane's C rows (per kb) = keys 8g + 4h + (0..3), g=r>>2.
        float rs = 0.f;
        unsigned int c0[2][4], c1[2][4];       // [kb][g] = packed keys {+0,+1}, {+2,+3}
#pragma unroll
        for (int kb = 0; kb < 2; ++kb)
#pragma unroll
            for (int g = 0; g < 4; ++g) {
                float p0 = exp2f(s[kb][4 * g + 0] * scale - m_q);
                float p1 = exp2f(s[kb][4 * g + 1] * scale - m_q);
                float p2 = exp2f(s[kb][4 * g + 2] * scale - m_q);
                float p3 = exp2f(s[kb][4 * g + 3] * scale - m_q);
                rs += (p0 + p1) + (p2 + p3);
                union { fp16x2 h2; unsigned int u; } u01, u23;
                u01.h2 = __builtin_amdgcn_cvt_pkrtz(p0, p1);
                u23.h2 = __builtin_amdgcn_cvt_pkrtz(p2, p3);
                c0[kb][g] = u01.u;
                c1[kb][g] = u23.u;
            }
        rs += __shfl_xor(rs, 32);
        l_q += rs;

        // next tile's K (sunk by compiler to use-points; TLP hides it)
        long kadv = (it + 1 < KT_PER) ? (long)64 * DD : 0;
        koff += kadv;
#pragma unroll
        for (int kb = 0; kb < 2; ++kb)
#pragma unroll
            for (int dc = 0; dc < 4; ++dc) {
                kh[kb][dc] = *(const half8*)(Khi + koff + kb * 32 * DD + dc * 16);
                kl[kb][dc] = *(const half8*)(Klo + koff + kb * 32 * DD + dc * 16);
            }

        // O += P V. A-frag keys for chunk kc come from groups {2(kc&1), 2(kc&1)+1};
        // permlane32_swap semantics: vdst[32:63] <-> src[0:31], i.e.
        //   ret[0] = {dst lanes 0-31 keep, lanes 32-63 get src's 0-31}
        //   ret[1] = {lanes 0-31 get dst's 32-63, lanes 32-63 keep}
        // giving frag dwords slot0/slot2 (c0 pair) and slot1/slot3 (c1 pair).
#pragma unroll
        for (int kc = 0; kc < 4; ++kc) {
            int kb = kc >> 1;
            int ge = (kc & 1) * 2;
            unsigned int a0 = c0[kb][ge], b0 = c0[kb][ge + 1];
            unsigned int a1 = c1[kb][ge], b1 = c1[kb][ge + 1];
            auto r0 = __builtin_amdgcn_permlane32_swap(a0, b0, false, false);
            auto r1 = __builtin_amdgcn_permlane32_swap(a1, b1, false, false);
            union { unsigned int u[4]; half8 h8; } pa;
            pa.u[0] = (unsigned int)r0[0];   // keys h'*8 + {0,1}
            pa.u[1] = (unsigned int)r1[0];   // keys h'*8 + {2,3}
            pa.u[2] = (unsigned int)r0[1];   // keys h'*8 + {4,5}
            pa.u[3] = (unsigned int)r1[1];   // keys h'*8 + {6,7}
            o0 = __builtin_amdgcn_mfma_f32_32x32x16_f16(pa.h8, vb[kc][0], o0, 0, 0, 0);
            o1 = __builtin_amdgcn_mfma_f32_32x32x16_f16(pa.h8, vb[kc][1], o1, 0, 0, 0);
        }

        // next tile's V
        long vadv = (it + 1 < KT_PER) ? 64 : 0;
        voff += vadv;
#pragma unroll
        for (int kc = 0; kc < 4; ++kc)
#pragma unroll
            for (int db = 0; db < 2; ++db)
                vb[kc][db] = *(const half8*)(Vt + voff + (long)db * 32 * SS + kc * 16);
    }

    // store unnormalized partial O (C rows = queries) and per-query (m, l)
    long pbase = ((long)b * NSPLIT + split) * SS;
    long obase = (pbase + q0w) * DD + col;
#pragma unroll
    for (int r = 0; r < 16; ++r) {
        long qrow = (r & 3) + 8 * (r >> 2) + 4 * h;
        Op[obase + qrow * DD]      = o0[r];
        Op[obase + qrow * DD + 32] = o1[r];
    }
    if (lane < 32) {
        Mp[pbase + q0w + col] = m_q;
        Lp[pbase + q0w + col] = l_q;
    }
}

// Kernel C: merge NSPLIT partials per query row. 16 queries/block.
__global__ __launch_bounds__(256) void combine_kernel(
    const float* __restrict__ Op, const float* __restrict__ Mp,
    const float* __restrict__ Lp, float* __restrict__ Out)
{
    int t = threadIdx.x;
    int qi = t >> 4;
    int d4 = (t & 15) * 4;
    long gq = (long)blockIdx.x * 16 + qi;    // global row in [0, BB*SS)
    int b = (int)(gq >> 12);
    int s = (int)(gq & 4095);

    float m = -1e30f;
    for (int i = 0; i < NSPLIT; ++i)
        m = fmaxf(m, Mp[((long)b * NSPLIT + i) * SS + s]);
    float l = 0.f;
    float4 o = {0.f, 0.f, 0.f, 0.f};
    for (int i = 0; i < NSPLIT; ++i) {
        long pb = ((long)b * NSPLIT + i) * SS + s;
        float a = exp2f(Mp[pb] - m);
        l = fmaf(Lp[pb], a, l);
        float4 oi = *(const float4*)(Op + pb * DD + d4);
        o.x = fmaf(oi.x, a, o.x); o.y = fmaf(oi.y, a, o.y);
        o.z = fmaf(oi.z, a, o.z); o.w = fmaf(oi.w, a, o.w);
    }
    float inv = 1.f / l;
    float4 r = {o.x * inv, o.y * inv, o.z * inv, o.w * inv};
    *(float4*)(Out + gq * DD + d4) = r;
}

extern "C" void kernel_launch(void* const* d_in, const int* in_sizes, int n_in,
                              void* d_out, int out_size, void* d_ws, size_t ws_size,
                              hipStream_t stream) {
    const float* X = (const float*)d_in[0];
    const float* R = (const float*)d_in[1];
    const float* E = (const float*)d_in[2];
    float* Out = (float*)d_out;

    const size_t N = (size_t)BB * SS * DD;
    _Float16* Qhi = (_Float16*)d_ws;
    _Float16* Qlo = Qhi + N;
    _Float16* Khi = Qlo + N;
    _Float16* Klo = Khi + N;
    _Float16* Vt  = Klo + N;                      // 10 MB fp16
    float* Op = (float*)(Vt + N);                 // BB*NSPLIT*SS*DD fp32 = 33.5 MB
    float* Mp = Op + (size_t)BB * NSPLIT * SS * DD;
    float* Lp = Mp + (size_t)BB * NSPLIT * SS;    // total ~44.6 MB

    proj_kernel<<<dim3(BB * SS / 16), 256, 0, stream>>>(X, R, E, Qhi, Qlo, Khi, Klo, Vt);
    attn_partial<<<dim3(BB * NSPLIT * (SS / 128)), 256, 0, stream>>>(Qhi, Qlo, Khi, Klo, Vt, Op, Mp, Lp);
    combine_kernel<<<dim3(BB * SS / 16), 256, 0, stream>>>(Op, Mp, Lp, Out);
}

// Round 4
// 165.455 us; speedup vs baseline: 1.2020x; 1.2020x over previous
//
#include <hip/hip_runtime.h>
#include <hip/hip_fp16.h>

#define BB 4
#define SS 4096
#define DD 64
#define NSPLIT 8                 // K-split factor: 1024 blocks = 4/CU = 16 waves/CU
#define KT_PER (SS / 64 / NSPLIT)

typedef _Float16 half8 __attribute__((ext_vector_type(8)));
typedef _Float16 half4 __attribute__((ext_vector_type(4)));
typedef __fp16 fp16x2 __attribute__((ext_vector_type(2)));   // cvt_pkrtz return type
typedef float floatx4 __attribute__((ext_vector_type(4)));
typedef float floatx16 __attribute__((ext_vector_type(16)));

// Kernel A: Q = X*R, K = X*E in fp32, stored as hi/lo fp16 pairs (Markidis split).
__global__ __launch_bounds__(256) void proj_kernel(
    const float* __restrict__ X, const float* __restrict__ R, const float* __restrict__ E,
    _Float16* __restrict__ Qhi, _Float16* __restrict__ Qlo,
    _Float16* __restrict__ Khi, _Float16* __restrict__ Klo,
    _Float16* __restrict__ Vt)
{
    __shared__ float Rs[64][64];
    __shared__ float Es[64][64];
    __shared__ float Xs[16][68];     // pad 68 breaks stride-64 conflicts on transposed reads
    int t = threadIdx.x;
    long rowbase = (long)blockIdx.x * 16;

    for (int j = 0; j < 4; ++j) {
        int idx = j * 256 + t;       // 1024 float4 per 64x64 matrix
        int r = idx >> 4;
        int c = (idx & 15) * 4;
        *(float4*)&Rs[r][c] = ((const float4*)R)[idx];
        *(float4*)&Es[r][c] = ((const float4*)E)[idx];
    }
    *(float4*)&Xs[t >> 4][(t & 15) * 4] = ((const float4*)(X + rowbase * 64))[t];
    __syncthreads();

    int row = t >> 4;                // 0..15
    int c0 = (t & 15) * 4;           // 0..60
    float q[4] = {0.f, 0.f, 0.f, 0.f}, k[4] = {0.f, 0.f, 0.f, 0.f};
#pragma unroll 4
    for (int d = 0; d < 64; ++d) {
        float x = Xs[row][d];
        float4 rv = *(const float4*)&Rs[d][c0];   // ds_read_b128
        float4 ev = *(const float4*)&Es[d][c0];
        q[0] = fmaf(x, rv.x, q[0]); q[1] = fmaf(x, rv.y, q[1]);
        q[2] = fmaf(x, rv.z, q[2]); q[3] = fmaf(x, rv.w, q[3]);
        k[0] = fmaf(x, ev.x, k[0]); k[1] = fmaf(x, ev.y, k[1]);
        k[2] = fmaf(x, ev.z, k[2]); k[3] = fmaf(x, ev.w, k[3]);
    }
    long gq = (rowbase + row) * 64 + c0;
    half4 qh, ql, kh, kl;
    for (int j = 0; j < 4; ++j) {
        _Float16 h = (_Float16)q[j];
        qh[j] = h; ql[j] = (_Float16)(q[j] - (float)h);
        h = (_Float16)k[j];
        kh[j] = h; kl[j] = (_Float16)(k[j] - (float)h);
    }
    *(half4*)(Qhi + gq) = qh; *(half4*)(Qlo + gq) = ql;
    *(half4*)(Khi + gq) = kh; *(half4*)(Klo + gq) = kl;

    // V^T: Vt[b][d][s] = X[b][s][d] fp16
    int d = t >> 2;                  // 0..63
    int si = (t & 3) * 4;            // 0..12
    int b = (int)(rowbase >> 12);
    int sbase = (int)(rowbase & 4095);
    half4 v;
    for (int j = 0; j < 4; ++j) v[j] = (_Float16)Xs[si + j][d];
    *(half4*)(Vt + ((long)(b * 64 + d)) * SS + sbase + si) = v;
}

#define L2E 1.44269504088896340736f

// Kernel B: flash attention partial, ZERO LDS.
// 32x32x16 MFMA, 32 queries/wave, S^T layout (A=K, B=Q) so each lane owns ONE
// query column (lane&31); partner lane is lane^32 (one shfl_xor per reduction).
// K/V fragments load straight from global (L1/L2-resident, shared by the 4 waves).
// P stays in registers: v_permlane32_swap_b32 builds the PV A-fragments (T12).
// R2: compiler sinks "prefetch" loads to uses (VGPR=84) — latency hidden by TLP:
// NSPLIT=8 -> 1024 blocks = 4/CU = 16 waves/CU.
// R3 lesson: launch_bounds(256,4) forced the 64-VGPR bucket -> 524 B/thread
// scratch spill (WRITE_SIZE 17->134 MB), attn 100->140us. Keep (256,2): VGPR=84,
// no spill; 84 <= 128-bucket so the GRID (not registers) sets 16 waves/CU.
__global__ __launch_bounds__(256, 2) void attn_partial(
    const _Float16* __restrict__ Qhi, const _Float16* __restrict__ Qlo,
    const _Float16* __restrict__ Khi, const _Float16* __restrict__ Klo,
    const _Float16* __restrict__ Vt,
    float* __restrict__ Op, float* __restrict__ Mp, float* __restrict__ Lp)
{
    int t = threadIdx.x;
    int wave = t >> 6;
    int lane = t & 63;
    int col = lane & 31;             // query column (QK C) == query row (PV A) == d col (PV C)
    int h = lane >> 5;               // lane half

    // XCD-aware decode: dispatch round-robins XCD = lin&7; give each XCD 4
    // contiguous (b,split) K-ranges so its L2 working set is ~770 KB.
    int lin = blockIdx.x;            // 0..1023
    int xcd = lin & 7;
    int idx = lin >> 3;              // 0..127
    int combo = xcd * 4 + (idx >> 5);// 0..31  (b,split) pair
    int qt = idx & 31;
    int b = combo >> 3;
    int split = combo & 7;

    int q0w = qt * 128 + wave * 32;

    const float scale = 0.125f * L2E;

    // Q B-fragments: B[k=dc*16+h*8+j][query=col], contiguous in Qhi[q][d]
    long qbase = ((long)b * SS + q0w + col) * DD + h * 8;
    half8 qh[4], ql[4];
#pragma unroll
    for (int dc = 0; dc < 4; ++dc) {
        qh[dc] = *(const half8*)(Qhi + qbase + dc * 16);
        ql[dc] = *(const half8*)(Qlo + qbase + dc * 16);
    }

    int kt0 = split * KT_PER;
    long koff = ((long)b * SS + (long)kt0 * 64 + col) * DD + h * 8;
    long voff = ((long)b * 64 + col) * SS + kt0 * 64 + h * 8;

    // tile-0 operand fragments (register-rotated each iteration; compiler may
    // sink these to use-points — fine, TLP covers the latency)
    half8 kh[2][4], kl[2][4], vb[4][2];
#pragma unroll
    for (int kb = 0; kb < 2; ++kb)
#pragma unroll
        for (int dc = 0; dc < 4; ++dc) {
            kh[kb][dc] = *(const half8*)(Khi + koff + kb * 32 * DD + dc * 16);
            kl[kb][dc] = *(const half8*)(Klo + koff + kb * 32 * DD + dc * 16);
        }
#pragma unroll
    for (int kc = 0; kc < 4; ++kc)
#pragma unroll
        for (int db = 0; db < 2; ++db)
            vb[kc][db] = *(const half8*)(Vt + voff + (long)db * 32 * SS + kc * 16);

    floatx16 o0 = {}, o1 = {};
    float m_q = -1e30f, l_q = 0.f;

#pragma unroll 1
    for (int it = 0; it < KT_PER; ++it) {
        // S^T = K Q^T (fp32-accurate, 3-term Markidis): C[key][query=col]
        floatx16 s[2] = {};
#pragma unroll
        for (int dc = 0; dc < 4; ++dc) {
            s[0] = __builtin_amdgcn_mfma_f32_32x32x16_f16(kh[0][dc], qh[dc], s[0], 0, 0, 0);
            s[1] = __builtin_amdgcn_mfma_f32_32x32x16_f16(kh[1][dc], qh[dc], s[1], 0, 0, 0);
            s[0] = __builtin_amdgcn_mfma_f32_32x32x16_f16(kh[0][dc], ql[dc], s[0], 0, 0, 0);
            s[1] = __builtin_amdgcn_mfma_f32_32x32x16_f16(kh[1][dc], ql[dc], s[1], 0, 0, 0);
            s[0] = __builtin_amdgcn_mfma_f32_32x32x16_f16(kl[0][dc], qh[dc], s[0], 0, 0, 0);
            s[1] = __builtin_amdgcn_mfma_f32_32x32x16_f16(kl[1][dc], qh[dc], s[1], 0, 0, 0);
        }

        // per-query max: 32 in-lane values + one partner exchange
        float mt = s[0][0];
#pragma unroll
        for (int r = 1; r < 16; ++r) mt = fmaxf(mt, s[0][r]);
#pragma unroll
        for (int r = 0; r < 16; ++r) mt = fmaxf(mt, s[1][r]);
        mt = fmaxf(mt, __shfl_xor(mt, 32));
        mt *= scale;

        // defer-max (T13): only rescale when some query's max grew by >8 (exp2 dom)
        if (!__all(mt <= m_q + 8.f)) {
            float mn = fmaxf(m_q, mt);
            float alpha = exp2f(m_q - mn);     // 0 on first tile
            m_q = mn;
            l_q *= alpha;
#pragma unroll
            for (int r = 0; r < 16; ++r) {     // o rows are queries: gather that query's alpha
                float a = __shfl(alpha, (r & 3) + 8 * (r >> 2) + 4 * h);
                o0[r] *= a; o1[r] *= a;
            }
        }

        // exp + fp16 pack. Lane's C rows (per kb) = keys 8g + 4h + (0..3), g=r>>2.
        float rs = 0.f;
        unsigned int c0[2][4], c1[2][4];       // [kb][g] = packed keys {+0,+1}, {+2,+3}
#pragma unroll
        for (int kb = 0; kb < 2; ++kb)
#pragma unroll
            for (int g = 0; g < 4; ++g) {
                float p0 = exp2f(s[kb][4 * g + 0] * scale - m_q);
                float p1 = exp2f(s[kb][4 * g + 1] * scale - m_q);
                float p2 = exp2f(s[kb][4 * g + 2] * scale - m_q);
                float p3 = exp2f(s[kb][4 * g + 3] * scale - m_q);
                rs += (p0 + p1) + (p2 + p3);
                union { fp16x2 h2; unsigned int u; } u01, u23;
                u01.h2 = __builtin_amdgcn_cvt_pkrtz(p0, p1);
                u23.h2 = __builtin_amdgcn_cvt_pkrtz(p2, p3);
                c0[kb][g] = u01.u;
                c1[kb][g] = u23.u;
            }
        rs += __shfl_xor(rs, 32);
        l_q += rs;

        // next tile's K (sunk by compiler to use-points; TLP hides it)
        long kadv = (it + 1 < KT_PER) ? (long)64 * DD : 0;
        koff += kadv;
#pragma unroll
        for (int kb = 0; kb < 2; ++kb)
#pragma unroll
            for (int dc = 0; dc < 4; ++dc) {
                kh[kb][dc] = *(const half8*)(Khi + koff + kb * 32 * DD + dc * 16);
                kl[kb][dc] = *(const half8*)(Klo + koff + kb * 32 * DD + dc * 16);
            }

        // O += P V. A-frag keys for chunk kc come from groups {2(kc&1), 2(kc&1)+1};
        // permlane32_swap semantics: vdst[32:63] <-> src[0:31], i.e.
        //   ret[0] = {dst lanes 0-31 keep, lanes 32-63 get src's 0-31}
        //   ret[1] = {lanes 0-31 get dst's 32-63, lanes 32-63 keep}
        // giving frag dwords slot0/slot2 (c0 pair) and slot1/slot3 (c1 pair).
#pragma unroll
        for (int kc = 0; kc < 4; ++kc) {
            int kb = kc >> 1;
            int ge = (kc & 1) * 2;
            unsigned int a0 = c0[kb][ge], b0 = c0[kb][ge + 1];
            unsigned int a1 = c1[kb][ge], b1 = c1[kb][ge + 1];
            auto r0 = __builtin_amdgcn_permlane32_swap(a0, b0, false, false);
            auto r1 = __builtin_amdgcn_permlane32_swap(a1, b1, false, false);
            union { unsigned int u[4]; half8 h8; } pa;
            pa.u[0] = (unsigned int)r0[0];   // keys h'*8 + {0,1}
            pa.u[1] = (unsigned int)r1[0];   // keys h'*8 + {2,3}
            pa.u[2] = (unsigned int)r0[1];   // keys h'*8 + {4,5}
            pa.u[3] = (unsigned int)r1[1];   // keys h'*8 + {6,7}
            o0 = __builtin_amdgcn_mfma_f32_32x32x16_f16(pa.h8, vb[kc][0], o0, 0, 0, 0);
            o1 = __builtin_amdgcn_mfma_f32_32x32x16_f16(pa.h8, vb[kc][1], o1, 0, 0, 0);
        }

        // next tile's V
        long vadv = (it + 1 < KT_PER) ? 64 : 0;
        voff += vadv;
#pragma unroll
        for (int kc = 0; kc < 4; ++kc)
#pragma unroll
            for (int db = 0; db < 2; ++db)
                vb[kc][db] = *(const half8*)(Vt + voff + (long)db * 32 * SS + kc * 16);
    }

    // store unnormalized partial O (C rows = queries) and per-query (m, l)
    long pbase = ((long)b * NSPLIT + split) * SS;
    long obase = (pbase + q0w) * DD + col;
#pragma unroll
    for (int r = 0; r < 16; ++r) {
        long qrow = (r & 3) + 8 * (r >> 2) + 4 * h;
        Op[obase + qrow * DD]      = o0[r];
        Op[obase + qrow * DD + 32] = o1[r];
    }
    if (lane < 32) {
        Mp[pbase + q0w + col] = m_q;
        Lp[pbase + q0w + col] = l_q;
    }
}

// Kernel C: merge NSPLIT partials per query row. 16 queries/block.
__global__ __launch_bounds__(256) void combine_kernel(
    const float* __restrict__ Op, const float* __restrict__ Mp,
    const float* __restrict__ Lp, float* __restrict__ Out)
{
    int t = threadIdx.x;
    int qi = t >> 4;
    int d4 = (t & 15) * 4;
    long gq = (long)blockIdx.x * 16 + qi;    // global row in [0, BB*SS)
    int b = (int)(gq >> 12);
    int s = (int)(gq & 4095);

    float m = -1e30f;
    for (int i = 0; i < NSPLIT; ++i)
        m = fmaxf(m, Mp[((long)b * NSPLIT + i) * SS + s]);
    float l = 0.f;
    float4 o = {0.f, 0.f, 0.f, 0.f};
    for (int i = 0; i < NSPLIT; ++i) {
        long pb = ((long)b * NSPLIT + i) * SS + s;
        float a = exp2f(Mp[pb] - m);
        l = fmaf(Lp[pb], a, l);
        float4 oi = *(const float4*)(Op + pb * DD + d4);
        o.x = fmaf(oi.x, a, o.x); o.y = fmaf(oi.y, a, o.y);
        o.z = fmaf(oi.z, a, o.z); o.w = fmaf(oi.w, a, o.w);
    }
    float inv = 1.f / l;
    float4 r = {o.x * inv, o.y * inv, o.z * inv, o.w * inv};
    *(float4*)(Out + gq * DD + d4) = r;
}

extern "C" void kernel_launch(void* const* d_in, const int* in_sizes, int n_in,
                              void* d_out, int out_size, void* d_ws, size_t ws_size,
                              hipStream_t stream) {
    const float* X = (const float*)d_in[0];
    const float* R = (const float*)d_in[1];
    const float* E = (const float*)d_in[2];
    float* Out = (float*)d_out;

    const size_t N = (size_t)BB * SS * DD;
    _Float16* Qhi = (_Float16*)d_ws;
    _Float16* Qlo = Qhi + N;
    _Float16* Khi = Qlo + N;
    _Float16* Klo = Khi + N;
    _Float16* Vt  = Klo + N;                      // 10 MB fp16
    float* Op = (float*)(Vt + N);                 // BB*NSPLIT*SS*DD fp32 = 33.5 MB
    float* Mp = Op + (size_t)BB * NSPLIT * SS * DD;
    float* Lp = Mp + (size_t)BB * NSPLIT * SS;    // total ~44.6 MB

    proj_kernel<<<dim3(BB * SS / 16), 256, 0, stream>>>(X, R, E, Qhi, Qlo, Khi, Klo, Vt);
    attn_partial<<<dim3(BB * NSPLIT * (SS / 128)), 256, 0, stream>>>(Qhi, Qlo, Khi, Klo, Vt, Op, Mp, Lp);
    combine_kernel<<<dim3(BB * SS / 16), 256, 0, stream>>>(Op, Mp, Lp, Out);
}

// Round 5
// 123.068 us; speedup vs baseline: 1.6159x; 1.3444x over previous
//
#include <hip/hip_runtime.h>
#include <hip/hip_fp16.h>

#define BB 4
#define SS 4096
#define DD 64
#define NSPLIT 4                 // K-split: 512 blocks = 2/CU (pipeline hides latency, not TLP)
#define KT_PER (SS / 64 / NSPLIT)

typedef _Float16 half8 __attribute__((ext_vector_type(8)));
typedef _Float16 half4 __attribute__((ext_vector_type(4)));
typedef __fp16 fp16x2 __attribute__((ext_vector_type(2)));   // cvt_pkrtz return type
typedef float floatx4 __attribute__((ext_vector_type(4)));
typedef float floatx16 __attribute__((ext_vector_type(16)));
typedef unsigned int uintx4 __attribute__((ext_vector_type(4)));

// Kernel A: Q = X*R, K = X*E in fp32, stored as hi/lo fp16 pairs (Markidis split).
__global__ __launch_bounds__(256) void proj_kernel(
    const float* __restrict__ X, const float* __restrict__ R, const float* __restrict__ E,
    _Float16* __restrict__ Qhi, _Float16* __restrict__ Qlo,
    _Float16* __restrict__ Khi, _Float16* __restrict__ Klo,
    _Float16* __restrict__ Vt)
{
    __shared__ float Rs[64][64];
    __shared__ float Es[64][64];
    __shared__ float Xs[16][68];     // pad 68 breaks stride-64 conflicts on transposed reads
    int t = threadIdx.x;
    long rowbase = (long)blockIdx.x * 16;

    for (int j = 0; j < 4; ++j) {
        int idx = j * 256 + t;       // 1024 float4 per 64x64 matrix
        int r = idx >> 4;
        int c = (idx & 15) * 4;
        *(float4*)&Rs[r][c] = ((const float4*)R)[idx];
        *(float4*)&Es[r][c] = ((const float4*)E)[idx];
    }
    *(float4*)&Xs[t >> 4][(t & 15) * 4] = ((const float4*)(X + rowbase * 64))[t];
    __syncthreads();

    int row = t >> 4;                // 0..15
    int c0 = (t & 15) * 4;           // 0..60
    float q[4] = {0.f, 0.f, 0.f, 0.f}, k[4] = {0.f, 0.f, 0.f, 0.f};
#pragma unroll 4
    for (int d = 0; d < 64; ++d) {
        float x = Xs[row][d];
        float4 rv = *(const float4*)&Rs[d][c0];   // ds_read_b128
        float4 ev = *(const float4*)&Es[d][c0];
        q[0] = fmaf(x, rv.x, q[0]); q[1] = fmaf(x, rv.y, q[1]);
        q[2] = fmaf(x, rv.z, q[2]); q[3] = fmaf(x, rv.w, q[3]);
        k[0] = fmaf(x, ev.x, k[0]); k[1] = fmaf(x, ev.y, k[1]);
        k[2] = fmaf(x, ev.z, k[2]); k[3] = fmaf(x, ev.w, k[3]);
    }
    long gq = (rowbase + row) * 64 + c0;
    half4 qh, ql, kh, kl;
    for (int j = 0; j < 4; ++j) {
        _Float16 h = (_Float16)q[j];
        qh[j] = h; ql[j] = (_Float16)(q[j] - (float)h);
        h = (_Float16)k[j];
        kh[j] = h; kl[j] = (_Float16)(k[j] - (float)h);
    }
    *(half4*)(Qhi + gq) = qh; *(half4*)(Qlo + gq) = ql;
    *(half4*)(Khi + gq) = kh; *(half4*)(Klo + gq) = kl;

    // V^T: Vt[b][d][s] = X[b][s][d] fp16
    int d = t >> 2;                  // 0..63
    int si = (t & 3) * 4;            // 0..12
    int b = (int)(rowbase >> 12);
    int sbase = (int)(rowbase & 4095);
    half4 v;
    for (int j = 0; j < 4; ++j) v[j] = (_Float16)Xs[si + j][d];
    *(half4*)(Vt + ((long)(b * 64 + d)) * SS + sbase + si) = v;
}

#define L2E 1.44269504088896340736f

// Kernel B: flash attention partial. 32x32x16 MFMA, S^T layout (A=K, B=Q), lane
// owns one query column; P stays in registers (permlane32_swap, T12).
// R4 lesson: zero-LDS needs ~150 unified regs -> hard 2 waves/SIMD cap; grid
// size can't raise occupancy; load-sinking exposes L2 latency every iter.
// This round: LDS-staged K(hi/lo)+V with m201 XOR swizzle (chunk^=(row&7), 16B
// granule) and a 2-phase T14 pipeline: staging loads for tile t+1 issue AFTER
// the barrier and are consumed by ds_write at iter t+1 top -> the barrier's
// vmcnt(0) drain waits on nothing; empty-asm pin defeats load re-sinking.
__global__ __launch_bounds__(256, 2) void attn_partial(
    const _Float16* __restrict__ Qhi, const _Float16* __restrict__ Qlo,
    const _Float16* __restrict__ Khi, const _Float16* __restrict__ Klo,
    const _Float16* __restrict__ Vt,
    float* __restrict__ Op, float* __restrict__ Mp, float* __restrict__ Lp)
{
    __shared__ _Float16 KhiS[2][64][64];   // 16 KB
    __shared__ _Float16 KloS[2][64][64];   // 16 KB
    __shared__ _Float16 VtS [2][64][64];   // 16 KB  (48 KB total, dbuf)

    int t = threadIdx.x;
    int w = t >> 6;                  // wave 0..3
    int lane = t & 63;
    int col = lane & 31;             // query column (QK C) == query row (PV A) == d col (PV C)
    int h = lane >> 5;               // lane half
    int l7 = lane & 7;

    // XCD-aware decode: 512 blocks; each XCD owns 2 contiguous (b,split) K-ranges.
    int lin = blockIdx.x;            // 0..511
    int xcd = lin & 7;
    int idx = lin >> 3;              // 0..63
    int combo = xcd * 2 + (idx >> 5);// 0..15
    int qt = idx & 31;
    int b = combo >> 2;
    int split = combo & 3;

    int q0w = qt * 128 + w * 32;

    const float scale = 0.125f * L2E;

    // Q B-fragments: B[k=dc*16+h*8+j][query=col], contiguous in Qhi[q][d]
    long qbase = ((long)b * SS + q0w + col) * DD + h * 8;
    half8 qfh[4], qfl[4];
#pragma unroll
    for (int dc = 0; dc < 4; ++dc) {
        qfh[dc] = *(const half8*)(Qhi + qbase + dc * 16);
        qfl[dc] = *(const half8*)(Qlo + qbase + dc * 16);
    }

    int kt0 = split * KT_PER;
    // staging: thread covers row=lane, 16B chunks {2w, 2w+1} of each 64x64 tile
    long kstage = ((long)b * SS + (long)kt0 * 64 + lane) * DD + w * 16;
    long vstage = ((long)b * 64 + lane) * SS + (long)kt0 * 64 + w * 16;

    // swizzled write offsets (halfs): slot delta -> ((2w+d)^(row&7))*8
    int ws0 = ((2 * w)     ^ l7) * 8;
    int ws1 = ((2 * w + 1) ^ l7) * 8;

    // prologue: issue tile-0 staging loads
    uintx4 skh0 = *(const uintx4*)(Khi + kstage);
    uintx4 skh1 = *(const uintx4*)(Khi + kstage + 8);
    uintx4 skl0 = *(const uintx4*)(Klo + kstage);
    uintx4 skl1 = *(const uintx4*)(Klo + kstage + 8);
    uintx4 sv0  = *(const uintx4*)(Vt + vstage);
    uintx4 sv1  = *(const uintx4*)(Vt + vstage + 8);

    floatx16 o0 = {}, o1 = {};
    float m_q = -1e30f, l_q = 0.f;

#pragma unroll 1
    for (int it = 0; it < KT_PER; ++it) {
        int buf = it & 1;
        // ds_write tile(it) into buf (compiler inserts vmcnt waits via data dep)
        *(uintx4*)&KhiS[buf][lane][ws0] = skh0;
        *(uintx4*)&KhiS[buf][lane][ws1] = skh1;
        *(uintx4*)&KloS[buf][lane][ws0] = skl0;
        *(uintx4*)&KloS[buf][lane][ws1] = skl1;
        *(uintx4*)&VtS [buf][lane][ws0] = sv0;
        *(uintx4*)&VtS [buf][lane][ws1] = sv1;
        __syncthreads();             // drain is ~free: nothing else in flight

        // issue tile(it+1) staging (clamped reload on last iter — harmless)
        long kadv = (it + 1 < KT_PER) ? (long)64 * DD : 0;
        long vadv = (it + 1 < KT_PER) ? 64 : 0;
        kstage += kadv; vstage += vadv;
        skh0 = *(const uintx4*)(Khi + kstage);
        skh1 = *(const uintx4*)(Khi + kstage + 8);
        skl0 = *(const uintx4*)(Klo + kstage);
        skl1 = *(const uintx4*)(Klo + kstage + 8);
        sv0  = *(const uintx4*)(Vt + vstage);
        sv1  = *(const uintx4*)(Vt + vstage + 8);

        // S^T = K Q^T (fp32-accurate, 3-term Markidis): C[key][query=col]
        floatx16 s[2] = {};
#pragma unroll
        for (int dc = 0; dc < 4; ++dc) {
            int rs = ((dc * 2 + h) ^ l7) * 8;     // swizzled read offset
            half8 k0h = *(const half8*)&KhiS[buf][col][rs];
            half8 k1h = *(const half8*)&KhiS[buf][32 + col][rs];
            half8 k0l = *(const half8*)&KloS[buf][col][rs];
            half8 k1l = *(const half8*)&KloS[buf][32 + col][rs];
            s[0] = __builtin_amdgcn_mfma_f32_32x32x16_f16(k0h, qfh[dc], s[0], 0, 0, 0);
            s[1] = __builtin_amdgcn_mfma_f32_32x32x16_f16(k1h, qfh[dc], s[1], 0, 0, 0);
            s[0] = __builtin_amdgcn_mfma_f32_32x32x16_f16(k0h, qfl[dc], s[0], 0, 0, 0);
            s[1] = __builtin_amdgcn_mfma_f32_32x32x16_f16(k1h, qfl[dc], s[1], 0, 0, 0);
            s[0] = __builtin_amdgcn_mfma_f32_32x32x16_f16(k0l, qfh[dc], s[0], 0, 0, 0);
            s[1] = __builtin_amdgcn_mfma_f32_32x32x16_f16(k1l, qfh[dc], s[1], 0, 0, 0);
        }

        // per-query max: 32 in-lane values + one partner exchange
        float mt = s[0][0];
#pragma unroll
        for (int r = 1; r < 16; ++r) mt = fmaxf(mt, s[0][r]);
#pragma unroll
        for (int r = 0; r < 16; ++r) mt = fmaxf(mt, s[1][r]);
        mt = fmaxf(mt, __shfl_xor(mt, 32));
        mt *= scale;

        // defer-max (T13): only rescale when some query's max grew by >8 (exp2 dom)
        if (!__all(mt <= m_q + 8.f)) {
            float mn = fmaxf(m_q, mt);
            float alpha = exp2f(m_q - mn);     // 0 on first tile
            m_q = mn;
            l_q *= alpha;
#pragma unroll
            for (int r = 0; r < 16; ++r) {     // o rows are queries: gather that query's alpha
                float a = __shfl(alpha, (r & 3) + 8 * (r >> 2) + 4 * h);
                o0[r] *= a; o1[r] *= a;
            }
        }

        // exp + fp16 pack. Lane's C rows (per kb) = keys 8g + 4h + (0..3), g=r>>2.
        float rs2 = 0.f;
        unsigned int c0[2][4], c1[2][4];       // [kb][g] = packed keys {+0,+1}, {+2,+3}
#pragma unroll
        for (int kb = 0; kb < 2; ++kb)
#pragma unroll
            for (int g = 0; g < 4; ++g) {
                float p0 = exp2f(s[kb][4 * g + 0] * scale - m_q);
                float p1 = exp2f(s[kb][4 * g + 1] * scale - m_q);
                float p2 = exp2f(s[kb][4 * g + 2] * scale - m_q);
                float p3 = exp2f(s[kb][4 * g + 3] * scale - m_q);
                rs2 += (p0 + p1) + (p2 + p3);
                union { fp16x2 h2; unsigned int u; } u01, u23;
                u01.h2 = __builtin_amdgcn_cvt_pkrtz(p0, p1);
                u23.h2 = __builtin_amdgcn_cvt_pkrtz(p2, p3);
                c0[kb][g] = u01.u;
                c1[kb][g] = u23.u;
            }
        rs2 += __shfl_xor(rs2, 32);
        l_q += rs2;

        // O += P V. permlane32_swap builds A-frags; V B-frags from swizzled LDS.
        //   ret[0] = {dst lanes 0-31 keep, lanes 32-63 get src's 0-31}
        //   ret[1] = {lanes 0-31 get dst's 32-63, lanes 32-63 keep}
#pragma unroll
        for (int kc = 0; kc < 4; ++kc) {
            int kb = kc >> 1;
            int ge = (kc & 1) * 2;
            unsigned int a0 = c0[kb][ge], b0 = c0[kb][ge + 1];
            unsigned int a1 = c1[kb][ge], b1 = c1[kb][ge + 1];
            auto r0 = __builtin_amdgcn_permlane32_swap(a0, b0, false, false);
            auto r1 = __builtin_amdgcn_permlane32_swap(a1, b1, false, false);
            union { unsigned int u[4]; half8 h8; } pa;
            pa.u[0] = (unsigned int)r0[0];   // keys h'*8 + {0,1}
            pa.u[1] = (unsigned int)r1[0];   // keys h'*8 + {2,3}
            pa.u[2] = (unsigned int)r0[1];   // keys h'*8 + {4,5}
            pa.u[3] = (unsigned int)r1[1];   // keys h'*8 + {6,7}
            int rsv = ((kc * 2 + h) ^ l7) * 8;
            half8 v0 = *(const half8*)&VtS[buf][col][rsv];
            half8 v1 = *(const half8*)&VtS[buf][32 + col][rsv];
            o0 = __builtin_amdgcn_mfma_f32_32x32x16_f16(pa.h8, v0, o0, 0, 0, 0);
            o1 = __builtin_amdgcn_mfma_f32_32x32x16_f16(pa.h8, v1, o1, 0, 0, 0);
        }

        // pin staged regs: forces completion here (cheap, ~600cy after issue)
        // and stops the compiler sinking the loads into the next iteration.
        asm volatile("" :: "v"(skh0), "v"(skh1), "v"(skl0), "v"(skl1), "v"(sv0), "v"(sv1));
    }

    // store unnormalized partial O (C rows = queries) and per-query (m, l)
    long pbase = ((long)b * NSPLIT + split) * SS;
    long obase = (pbase + q0w) * DD + col;
#pragma unroll
    for (int r = 0; r < 16; ++r) {
        long qrow = (r & 3) + 8 * (r >> 2) + 4 * h;
        Op[obase + qrow * DD]      = o0[r];
        Op[obase + qrow * DD + 32] = o1[r];
    }
    if (lane < 32) {
        Mp[pbase + q0w + col] = m_q;
        Lp[pbase + q0w + col] = l_q;
    }
}

// Kernel C: merge NSPLIT partials per query row. 16 queries/block.
__global__ __launch_bounds__(256) void combine_kernel(
    const float* __restrict__ Op, const float* __restrict__ Mp,
    const float* __restrict__ Lp, float* __restrict__ Out)
{
    int t = threadIdx.x;
    int qi = t >> 4;
    int d4 = (t & 15) * 4;
    long gq = (long)blockIdx.x * 16 + qi;    // global row in [0, BB*SS)
    int b = (int)(gq >> 12);
    int s = (int)(gq & 4095);

    float m = -1e30f;
    for (int i = 0; i < NSPLIT; ++i)
        m = fmaxf(m, Mp[((long)b * NSPLIT + i) * SS + s]);
    float l = 0.f;
    float4 o = {0.f, 0.f, 0.f, 0.f};
    for (int i = 0; i < NSPLIT; ++i) {
        long pb = ((long)b * NSPLIT + i) * SS + s;
        float a = exp2f(Mp[pb] - m);
        l = fmaf(Lp[pb], a, l);
        float4 oi = *(const float4*)(Op + pb * DD + d4);
        o.x = fmaf(oi.x, a, o.x); o.y = fmaf(oi.y, a, o.y);
        o.z = fmaf(oi.z, a, o.z); o.w = fmaf(oi.w, a, o.w);
    }
    float inv = 1.f / l;
    float4 r = {o.x * inv, o.y * inv, o.z * inv, o.w * inv};
    *(float4*)(Out + gq * DD + d4) = r;
}

extern "C" void kernel_launch(void* const* d_in, const int* in_sizes, int n_in,
                              void* d_out, int out_size, void* d_ws, size_t ws_size,
                              hipStream_t stream) {
    const float* X = (const float*)d_in[0];
    const float* R = (const float*)d_in[1];
    const float* E = (const float*)d_in[2];
    float* Out = (float*)d_out;

    const size_t N = (size_t)BB * SS * DD;
    _Float16* Qhi = (_Float16*)d_ws;
    _Float16* Qlo = Qhi + N;
    _Float16* Khi = Qlo + N;
    _Float16* Klo = Khi + N;
    _Float16* Vt  = Klo + N;                      // 10 MB fp16
    float* Op = (float*)(Vt + N);                 // BB*NSPLIT*SS*DD fp32 = 16.8 MB
    float* Mp = Op + (size_t)BB * NSPLIT * SS * DD;
    float* Lp = Mp + (size_t)BB * NSPLIT * SS;    // total ~27.3 MB

    proj_kernel<<<dim3(BB * SS / 16), 256, 0, stream>>>(X, R, E, Qhi, Qlo, Khi, Klo, Vt);
    attn_partial<<<dim3(BB * NSPLIT * (SS / 128)), 256, 0, stream>>>(Qhi, Qlo, Khi, Klo, Vt, Op, Mp, Lp);
    combine_kernel<<<dim3(BB * SS / 16), 256, 0, stream>>>(Op, Mp, Lp, Out);
}